// Round 1
// 658.833 us; speedup vs baseline: 1.0052x; 1.0052x over previous
//
#include <hip/hip_runtime.h>

// SlidingWindowAttention: S=512, L=2048, WINDOW=64, STRIDE=32 -> NW=63, E=64, H=8, HD=8
// ALL inputs and outputs are float32 (per reference setup_inputs). Internal compute
// uses bf16 MFMA fragments (converted from f32) + fp32 VALU attention body.
//
// R1 change: pin register budget with amdgpu_waves_per_eu(2,2).
// Evidence: WRITE_SIZE=587MB vs 74MB of actual output (7.9x over-write) and
// FETCH_SIZE=500MB vs ~280MB expected => ~1GB of scratch spill traffic. Peak live
// regs (accw[64]+sc[64]+kreg[64]/p[64] ~= 200-225) vs compiled VGPR_Count=128:
// LLVM targeted 4 waves/EU not knowing LDS (73KB -> 2 blocks/CU) already caps
// occupancy at 2 waves/EU, where 256 VGPRs are free. Pinning (2,2) lifts the
// budget to 256 and eliminates the spills.
#define S_DIM 512
#define L_DIM 2048
#define NW 63
#define E_DIM 64
#define NH 8
#define HD 8

typedef __bf16 bf16_t;
typedef __bf16 bf16x8 __attribute__((ext_vector_type(8)));
typedef float f32x4 __attribute__((ext_vector_type(4)));

// 8 consecutive f32 -> bf16x8 MFMA fragment (RNE converts)
__device__ inline bf16x8 cvt8(const float* __restrict__ p) {
    float4 a = *(const float4*)p;
    float4 b = *(const float4*)(p + 4);
    bf16x8 r;
    r[0] = (bf16_t)a.x; r[1] = (bf16_t)a.y; r[2] = (bf16_t)a.z; r[3] = (bf16_t)a.w;
    r[4] = (bf16_t)b.x; r[5] = (bf16_t)b.y; r[6] = (bf16_t)b.z; r[7] = (bf16_t)b.w;
    return r;
}

// Register transpose-reduce: after the 6 steps lane L holds the sum over all
// 64 lanes of item L.
#define RSTEP(B, CNT)                                              \
    {                                                              \
        bool up = (lane & B) != 0;                                 \
        _Pragma("unroll") for (int i = 0; i < CNT; ++i)            \
        {                                                          \
            float keep = up ? p[2 * i + 1] : p[2 * i];             \
            float send = up ? p[2 * i] : p[2 * i + 1];             \
            p[i] = keep + __shfl_xor(send, B, 64);                 \
        }                                                          \
    }

__attribute__((amdgpu_waves_per_eu(2, 2)))
__global__ __launch_bounds__(256) void swa_fused(
    const float* __restrict__ q, const float* __restrict__ k,
    const float* __restrict__ v, const float* __restrict__ w,
    const float* __restrict__ bias, const float* __restrict__ wout,
    const float* __restrict__ bout, float* __restrict__ out)
{
    // kp_s/vp_s: [512][16] head-pair projections (bf16), padded to 24
    // (48B row stride: 16B-aligned, conflict-free for ds_read_b128).
    __shared__ __align__(16) bf16_t kp_s[S_DIM][24];
    __shared__ __align__(16) bf16_t vp_s[S_DIM][24];
    __shared__ float  qp_s[32][64];      // this tile's scaled qp, fp32
    __shared__ float  ctx_s[32][68];
    __shared__ bf16_t wo_t[64][66];      // wo transposed: [f][e]
    __shared__ float  bo_s[64];

    int tid  = threadIdx.x;
    int lane = tid & 63, wave = tid >> 6;
    int bid  = blockIdx.x;
    int n    = bid >> 4;             // 63 windows x 16 row-tiles
    int tile = bid & 15;
    int srow0 = tile * 32;

    float* out_x  = out;
    float* out_aw = out + (size_t)S_DIM * NW * E_DIM;

    // ---- stage out-proj (transposed) + bias; first hp barrier orders these ----
#pragma unroll
    for (int i = 0; i < 16; ++i) {
        int idx = tid + i * 256;                    // idx = e*64 + f
        wo_t[idx & 63][idx >> 6] = (bf16_t)wout[idx];
    }
    if (tid < 64) bo_s[tid] = bout[tid];

    int ml = lane & 15, quad = lane >> 4;

    // ---- qp for this block's 32 rows via MFMA (waves 0,1), scale*log2e folded ----
    if (wave < 2) {
        int s0 = srow0 + wave * 16;
        f32x4 acc[4];
#pragma unroll
        for (int et = 0; et < 4; ++et) {
            float bv = bias[et * 16 + ml];
            acc[et] = (f32x4){bv, bv, bv, bv};
        }
        int arow = (s0 + ml) * L_DIM + 32 * n + quad * 8;
#pragma unroll
        for (int k0 = 0; k0 < 64; k0 += 32) {
            bf16x8 afrag = cvt8(q + arow + k0);
#pragma unroll
            for (int et = 0; et < 4; ++et) {
                bf16x8 bfrag = cvt8(w + (et * 16 + ml) * 64 + k0 + quad * 8);
                acc[et] = __builtin_amdgcn_mfma_f32_16x16x32_bf16(afrag, bfrag, acc[et], 0, 0, 0);
            }
        }
        const float cs = 0.35355339059327373f * 1.4426950408889634f;
#pragma unroll
        for (int et = 0; et < 4; ++et)
#pragma unroll
            for (int rr = 0; rr < 4; ++rr)
                qp_s[16 * wave + quad * 4 + rr][et * 16 + ml] = acc[et][rr] * cs;
    }

    float accw[64];   // attn-weight mean accumulator [r][j]
#pragma unroll
    for (int i = 0; i < 64; ++i) accw[i] = 0.f;

    for (int hp = 0; hp < 4; ++hp) {
        __syncthreads();   // prev readers done (also orders qp/wo/bo stores at hp=0)

        // ---- stage kp/vp[512][16] for heads {2hp, 2hp+1} via MFMA ----
#pragma unroll
        for (int i = 0; i < 8; ++i) {
            int s0 = wave * 128 + 16 * i;
            int arow = (s0 + ml) * L_DIM + 32 * n + quad * 8;
            float bk0 = bias[64 + hp * 16 + ml];
            float bv0 = bias[128 + hp * 16 + ml];
            f32x4 kacc = (f32x4){bk0, bk0, bk0, bk0};
            f32x4 vacc = (f32x4){bv0, bv0, bv0, bv0};
#pragma unroll
            for (int k0 = 0; k0 < 64; k0 += 32) {
                bf16x8 ak = cvt8(k + arow + k0);
                bf16x8 av = cvt8(v + arow + k0);
                bf16x8 bk = cvt8(w + (64 + hp * 16 + ml) * 64 + k0 + quad * 8);
                bf16x8 bv = cvt8(w + (128 + hp * 16 + ml) * 64 + k0 + quad * 8);
                kacc = __builtin_amdgcn_mfma_f32_16x16x32_bf16(ak, bk, kacc, 0, 0, 0);
                vacc = __builtin_amdgcn_mfma_f32_16x16x32_bf16(av, bv, vacc, 0, 0, 0);
            }
#pragma unroll
            for (int rr = 0; rr < 4; ++rr) {
                kp_s[s0 + quad * 4 + rr][ml] = (bf16_t)kacc[rr];
                vp_s[s0 + quad * 4 + rr][ml] = (bf16_t)vacc[rr];
            }
        }
        __syncthreads();

#pragma unroll
        for (int h01 = 0; h01 < 2; ++h01) {
            int h = hp * 2 + h01;

            // K fragment from LDS (b128, conflict-free), cvt to fp32
            float kreg[64];
#pragma unroll
            for (int j = 0; j < 8; ++j) {
                int t = lane + 64 * j;
                bf16x8 kb = *(const bf16x8*)(&kp_s[t][h01 * 8]);
#pragma unroll
                for (int d = 0; d < 8; ++d) kreg[j * 8 + d] = (float)kb[d];
            }

            // scores (log2 domain; scale*log2e folded into qp)
            float sc[64];
#pragma unroll
            for (int r = 0; r < 8; ++r) {
                float qreg[8];
#pragma unroll
                for (int d = 0; d < 8; ++d) qreg[d] = qp_s[wave * 8 + r][h * 8 + d];
#pragma unroll
                for (int j = 0; j < 8; ++j) {
                    float s = 0.f;
#pragma unroll
                    for (int d = 0; d < 8; ++d) s = fmaf(qreg[d], kreg[j * 8 + d], s);
                    sc[r * 8 + j] = s;
                }
            }

            // softmax per row (row = one wave: 64 lanes x 8 j) + mean accum
#pragma unroll
            for (int r = 0; r < 8; ++r) {
                float mx = sc[r * 8];
#pragma unroll
                for (int j = 1; j < 8; ++j) mx = fmaxf(mx, sc[r * 8 + j]);
#pragma unroll
                for (int b = 1; b < 64; b <<= 1) mx = fmaxf(mx, __shfl_xor(mx, b, 64));
                float l = 0.f;
#pragma unroll
                for (int j = 0; j < 8; ++j) {
                    float e = exp2f(sc[r * 8 + j] - mx);
                    sc[r * 8 + j] = e;
                    l += e;
                }
#pragma unroll
                for (int b = 1; b < 64; b <<= 1) l += __shfl_xor(l, b, 64);
                float inv = 1.0f / l;
#pragma unroll
                for (int j = 0; j < 8; ++j) {
                    float a = sc[r * 8 + j] * inv;
                    sc[r * 8 + j] = a;
                    accw[r * 8 + j] = fmaf(a, 0.125f, accw[r * 8 + j]);
                }
            }

            // ctx partials from LDS V, then register transpose-reduce
            float p[64];
#pragma unroll
            for (int i = 0; i < 64; ++i) p[i] = 0.f;
#pragma unroll
            for (int j = 0; j < 8; ++j) {
                int t = lane + 64 * j;
                bf16x8 vb = *(const bf16x8*)(&vp_s[t][h01 * 8]);
                float vr[8];
#pragma unroll
                for (int d = 0; d < 8; ++d) vr[d] = (float)vb[d];
#pragma unroll
                for (int r = 0; r < 8; ++r) {
                    float a = sc[r * 8 + j];
#pragma unroll
                    for (int d = 0; d < 8; ++d)
                        p[r * 8 + d] = fmaf(a, vr[d], p[r * 8 + d]);
                }
            }
            RSTEP(1, 32) RSTEP(2, 16) RSTEP(4, 8) RSTEP(8, 4) RSTEP(16, 2) RSTEP(32, 1)
            // lane holds ctx for (r = lane>>3, d = lane&7)
            ctx_s[wave * 8 + (lane >> 3)][h * 8 + (lane & 7)] = p[0];
        }
    }
    __syncthreads();

    // ---- attn_weights [NW][S][S] f32: lanes contiguous in t -> coalesced ----
#pragma unroll
    for (int r = 0; r < 8; ++r) {
        int s = srow0 + wave * 8 + r;
        float* dst = out_aw + ((size_t)(n * S_DIM + s)) * S_DIM + lane;
#pragma unroll
        for (int j = 0; j < 8; ++j) dst[64 * j] = accw[r * 8 + j];
    }

    // ---- out projection: x[s][e] = sum_f ctx[s][f] * Wout[e][f] + bout[e] ----
    int so = tid >> 3;   // 0..31
    int eb = tid & 7;
    float xacc[8];
#pragma unroll
    for (int kk = 0; kk < 8; ++kk) xacc[kk] = bo_s[eb + 8 * kk];
#pragma unroll
    for (int f = 0; f < 64; ++f) {
        float c = ctx_s[so][f];
#pragma unroll
        for (int kk = 0; kk < 8; ++kk)
            xacc[kk] = fmaf(c, (float)wo_t[f][eb + 8 * kk], xacc[kk]);
    }
    int sg = srow0 + so;
#pragma unroll
    for (int kk = 0; kk < 8; ++kk)
        out_x[((size_t)sg * NW + n) * E_DIM + eb + 8 * kk] = xacc[kk];
}

extern "C" void kernel_launch(void* const* d_in, const int* in_sizes, int n_in,
                              void* d_out, int out_size, void* d_ws, size_t ws_size,
                              hipStream_t stream) {
    const float* q  = (const float*)d_in[0];
    const float* k  = (const float*)d_in[1];
    const float* v  = (const float*)d_in[2];
    const float* w  = (const float*)d_in[3];
    const float* b  = (const float*)d_in[4];
    const float* wo = (const float*)d_in[5];
    const float* bo = (const float*)d_in[6];
    float* out = (float*)d_out;

    // 63 windows * 16 row-tiles = 1008 blocks; zero workspace used.
    hipLaunchKernelGGL(swa_fused, dim3(NW * 16), dim3(256), 0, stream,
                       q, k, v, w, b, wo, bo, out);
}

// Round 2
// 490.155 us; speedup vs baseline: 1.3512x; 1.3441x over previous
//
#include <hip/hip_runtime.h>

// SlidingWindowAttention: S=512, L=2048, WINDOW=64, STRIDE=32 -> NW=63, E=64, H=8, HD=8
// ALL inputs and outputs are float32. Internal compute uses bf16 MFMA fragments
// (converted from f32) for projections + fp32 VALU attention body.
//
// R2 change: 512-thread blocks, 4 q-rows per wave (was 256 thr / 8 rows per wave).
// Evidence: WRITE_SIZE excess = 513MB = 8 h01-iters x 256thr x 1008blk x 64 regs
// x 4B exactly -> accw[64] spilled to scratch and written back every head iter
// (VGPR_Count pinned at 128; waves_per_eu attr was a no-op in R1). With 4 rows
// per wave the live set is accw[32]+sc[32]+{kreg-half[32] | p[32]} ~= 104, which
// honestly fits 128 regs -> no scratch. Same 1008 blocks / 32-row tiles, LDS
// unchanged (74.8KB, 2 blocks/CU) -> occupancy doubles to 16 waves/CU.
#define S_DIM 512
#define L_DIM 2048
#define NW 63
#define E_DIM 64
#define NH 8
#define HD 8

typedef __bf16 bf16_t;
typedef __bf16 bf16x8 __attribute__((ext_vector_type(8)));
typedef float f32x4 __attribute__((ext_vector_type(4)));

// 8 consecutive f32 -> bf16x8 MFMA fragment (RNE converts)
__device__ inline bf16x8 cvt8(const float* __restrict__ p) {
    float4 a = *(const float4*)p;
    float4 b = *(const float4*)(p + 4);
    bf16x8 r;
    r[0] = (bf16_t)a.x; r[1] = (bf16_t)a.y; r[2] = (bf16_t)a.z; r[3] = (bf16_t)a.w;
    r[4] = (bf16_t)b.x; r[5] = (bf16_t)b.y; r[6] = (bf16_t)b.z; r[7] = (bf16_t)b.w;
    return r;
}

// Register transpose-reduce over 32 items spread across 64 lanes.
// After the 5 steps each 32-lane half holds, in lane l (l = lane&31), the
// half-sum of item l; a final shfl_xor(...,32) makes it the full 64-lane sum.
#define RSTEP(B, CNT)                                              \
    {                                                              \
        bool up = (lane & B) != 0;                                 \
        _Pragma("unroll") for (int i = 0; i < CNT; ++i)            \
        {                                                          \
            float keep = up ? p[2 * i + 1] : p[2 * i];             \
            float send = up ? p[2 * i] : p[2 * i + 1];             \
            p[i] = keep + __shfl_xor(send, B, 64);                 \
        }                                                          \
    }

__global__ __launch_bounds__(512, 2) void swa_fused(
    const float* __restrict__ q, const float* __restrict__ k,
    const float* __restrict__ v, const float* __restrict__ w,
    const float* __restrict__ bias, const float* __restrict__ wout,
    const float* __restrict__ bout, float* __restrict__ out)
{
    // kp_s/vp_s: [512][16] head-pair projections (bf16), padded to 24
    // (48B row stride: 16B-aligned; ds_read_b128 2-way conflicts only = free).
    __shared__ __align__(16) bf16_t kp_s[S_DIM][24];
    __shared__ __align__(16) bf16_t vp_s[S_DIM][24];
    __shared__ float  qp_s[32][64];      // this tile's scaled qp, fp32
    __shared__ float  ctx_s[32][68];
    __shared__ bf16_t wo_t[64][66];      // wo transposed: [f][e]
    __shared__ float  bo_s[64];

    int tid  = threadIdx.x;
    int lane = tid & 63, wave = tid >> 6;   // 8 waves
    int bid  = blockIdx.x;
    int n    = bid >> 4;             // 63 windows x 16 row-tiles
    int tile = bid & 15;
    int srow0 = tile * 32;

    float* out_x  = out;
    float* out_aw = out + (size_t)S_DIM * NW * E_DIM;

    // ---- stage out-proj (transposed) + bias; first hp barrier orders these ----
#pragma unroll
    for (int i = 0; i < 8; ++i) {
        int idx = tid + i * 512;                    // idx = e*64 + f
        wo_t[idx & 63][idx >> 6] = (bf16_t)wout[idx];
    }
    if (tid < 64) bo_s[tid] = bout[tid];

    int ml = lane & 15, quad = lane >> 4;

    // ---- qp for this block's 32 rows via MFMA (waves 0,1), scale*log2e folded ----
    if (wave < 2) {
        int s0 = srow0 + wave * 16;
        f32x4 acc[4];
#pragma unroll
        for (int et = 0; et < 4; ++et) {
            float bv = bias[et * 16 + ml];
            acc[et] = (f32x4){bv, bv, bv, bv};
        }
        int arow = (s0 + ml) * L_DIM + 32 * n + quad * 8;
#pragma unroll
        for (int k0 = 0; k0 < 64; k0 += 32) {
            bf16x8 afrag = cvt8(q + arow + k0);
#pragma unroll
            for (int et = 0; et < 4; ++et) {
                bf16x8 bfrag = cvt8(w + (et * 16 + ml) * 64 + k0 + quad * 8);
                acc[et] = __builtin_amdgcn_mfma_f32_16x16x32_bf16(afrag, bfrag, acc[et], 0, 0, 0);
            }
        }
        const float cs = 0.35355339059327373f * 1.4426950408889634f;
#pragma unroll
        for (int et = 0; et < 4; ++et)
#pragma unroll
            for (int rr = 0; rr < 4; ++rr)
                qp_s[16 * wave + quad * 4 + rr][et * 16 + ml] = acc[et][rr] * cs;
    }

    float accw[32];   // attn-weight mean accumulator [r][j], r<4
#pragma unroll
    for (int i = 0; i < 32; ++i) accw[i] = 0.f;

    for (int hp = 0; hp < 4; ++hp) {
        __syncthreads();   // prev readers done (also orders qp/wo/bo stores at hp=0)

        // ---- stage kp/vp[512][16] for heads {2hp, 2hp+1} via MFMA ----
#pragma unroll
        for (int i = 0; i < 4; ++i) {
            int s0 = wave * 64 + 16 * i;
            int arow = (s0 + ml) * L_DIM + 32 * n + quad * 8;
            float bk0 = bias[64 + hp * 16 + ml];
            float bv0 = bias[128 + hp * 16 + ml];
            f32x4 kacc = (f32x4){bk0, bk0, bk0, bk0};
            f32x4 vacc = (f32x4){bv0, bv0, bv0, bv0};
#pragma unroll
            for (int k0 = 0; k0 < 64; k0 += 32) {
                bf16x8 ak = cvt8(k + arow + k0);
                bf16x8 av = cvt8(v + arow + k0);
                bf16x8 bk = cvt8(w + (64 + hp * 16 + ml) * 64 + k0 + quad * 8);
                bf16x8 bv = cvt8(w + (128 + hp * 16 + ml) * 64 + k0 + quad * 8);
                kacc = __builtin_amdgcn_mfma_f32_16x16x32_bf16(ak, bk, kacc, 0, 0, 0);
                vacc = __builtin_amdgcn_mfma_f32_16x16x32_bf16(av, bv, vacc, 0, 0, 0);
            }
#pragma unroll
            for (int rr = 0; rr < 4; ++rr) {
                kp_s[s0 + quad * 4 + rr][ml] = (bf16_t)kacc[rr];
                vp_s[s0 + quad * 4 + rr][ml] = (bf16_t)vacc[rr];
            }
        }
        __syncthreads();

#pragma unroll
        for (int h01 = 0; h01 < 2; ++h01) {
            int h = hp * 2 + h01;

            // scores (log2 domain; scale*log2e folded into qp).
            // K streamed in two 32-reg halves to keep live set small.
            float sc[32];
#pragma unroll
            for (int half = 0; half < 2; ++half) {
                float kreg[32];
#pragma unroll
                for (int j = 0; j < 4; ++j) {
                    int t = lane + 64 * (half * 4 + j);
                    bf16x8 kb = *(const bf16x8*)(&kp_s[t][h01 * 8]);
#pragma unroll
                    for (int d = 0; d < 8; ++d) kreg[j * 8 + d] = (float)kb[d];
                }
#pragma unroll
                for (int r = 0; r < 4; ++r) {
                    float qreg[8];
#pragma unroll
                    for (int d = 0; d < 8; ++d) qreg[d] = qp_s[wave * 4 + r][h * 8 + d];
#pragma unroll
                    for (int j = 0; j < 4; ++j) {
                        float s = 0.f;
#pragma unroll
                        for (int d = 0; d < 8; ++d) s = fmaf(qreg[d], kreg[j * 8 + d], s);
                        sc[r * 8 + half * 4 + j] = s;
                    }
                }
            }

            // softmax per row (row = one wave: 64 lanes x 8 j) + mean accum
#pragma unroll
            for (int r = 0; r < 4; ++r) {
                float mx = sc[r * 8];
#pragma unroll
                for (int j = 1; j < 8; ++j) mx = fmaxf(mx, sc[r * 8 + j]);
#pragma unroll
                for (int b = 1; b < 64; b <<= 1) mx = fmaxf(mx, __shfl_xor(mx, b, 64));
                float l = 0.f;
#pragma unroll
                for (int j = 0; j < 8; ++j) {
                    float e = exp2f(sc[r * 8 + j] - mx);
                    sc[r * 8 + j] = e;
                    l += e;
                }
#pragma unroll
                for (int b = 1; b < 64; b <<= 1) l += __shfl_xor(l, b, 64);
                float inv = 1.0f / l;
#pragma unroll
                for (int j = 0; j < 8; ++j) {
                    float a = sc[r * 8 + j] * inv;
                    sc[r * 8 + j] = a;
                    accw[r * 8 + j] = fmaf(a, 0.125f, accw[r * 8 + j]);
                }
            }

            // ctx partials from LDS V, then register transpose-reduce (32 items)
            float p[32];
#pragma unroll
            for (int i = 0; i < 32; ++i) p[i] = 0.f;
#pragma unroll
            for (int j = 0; j < 8; ++j) {
                int t = lane + 64 * j;
                bf16x8 vb = *(const bf16x8*)(&vp_s[t][h01 * 8]);
                float vr[8];
#pragma unroll
                for (int d = 0; d < 8; ++d) vr[d] = (float)vb[d];
#pragma unroll
                for (int r = 0; r < 4; ++r) {
                    float a = sc[r * 8 + j];
#pragma unroll
                    for (int d = 0; d < 8; ++d)
                        p[r * 8 + d] = fmaf(a, vr[d], p[r * 8 + d]);
                }
            }
            RSTEP(1, 16) RSTEP(2, 8) RSTEP(4, 4) RSTEP(8, 2) RSTEP(16, 1)
            p[0] += __shfl_xor(p[0], 32, 64);
            // lane&31 holds ctx for (r = (lane&31)>>3, d = lane&7); halves identical
            if (lane < 32)
                ctx_s[wave * 4 + (lane >> 3)][h * 8 + (lane & 7)] = p[0];
        }
    }
    __syncthreads();

    // ---- attn_weights [NW][S][S] f32: lanes contiguous in t -> coalesced ----
#pragma unroll
    for (int r = 0; r < 4; ++r) {
        int s = srow0 + wave * 4 + r;
        float* dst = out_aw + ((size_t)(n * S_DIM + s)) * S_DIM + lane;
#pragma unroll
        for (int j = 0; j < 8; ++j) dst[64 * j] = accw[r * 8 + j];
    }

    // ---- out projection: x[s][e] = sum_f ctx[s][f] * Wout[e][f] + bout[e] ----
    int so = tid >> 4;   // 0..31
    int eb = tid & 15;
    float xacc[4];
#pragma unroll
    for (int kk = 0; kk < 4; ++kk) xacc[kk] = bo_s[eb + 16 * kk];
#pragma unroll
    for (int f = 0; f < 64; ++f) {
        float c = ctx_s[so][f];
#pragma unroll
        for (int kk = 0; kk < 4; ++kk)
            xacc[kk] = fmaf(c, (float)wo_t[f][eb + 16 * kk], xacc[kk]);
    }
    int sg = srow0 + so;
#pragma unroll
    for (int kk = 0; kk < 4; ++kk)
        out_x[((size_t)sg * NW + n) * E_DIM + eb + 16 * kk] = xacc[kk];
}

extern "C" void kernel_launch(void* const* d_in, const int* in_sizes, int n_in,
                              void* d_out, int out_size, void* d_ws, size_t ws_size,
                              hipStream_t stream) {
    const float* q  = (const float*)d_in[0];
    const float* k  = (const float*)d_in[1];
    const float* v  = (const float*)d_in[2];
    const float* w  = (const float*)d_in[3];
    const float* b  = (const float*)d_in[4];
    const float* wo = (const float*)d_in[5];
    const float* bo = (const float*)d_in[6];
    float* out = (float*)d_out;

    // 63 windows * 16 row-tiles = 1008 blocks of 512 threads.
    hipLaunchKernelGGL(swa_fused, dim3(NW * 16), dim3(512), 0, stream,
                       q, k, v, w, b, wo, bo, out);
}

// Round 3
// 299.977 us; speedup vs baseline: 2.2078x; 1.6340x over previous
//
#include <hip/hip_runtime.h>

// SlidingWindowAttention: S=512, L=2048, WINDOW=64, STRIDE=32 -> NW=63, E=64, H=8, HD=8
// ALL inputs and outputs are float32. Internal compute uses bf16 MFMA fragments
// (converted from f32) for projections + fp32 VALU attention body.
//
// R3 changes (from R2 @ 433us profiled: Occ 23.6% == 1 block/CU, VALUBusy 35%,
// MfmaUtil 0.8%, HBM 3% -> latency-bound at 2 waves/SIMD):
//  1. LDS 74752 -> 58368 B: kp/vp as [2][512][8] bf16 (16B rows). Tests the
//     "LDS caps us at 1 block/CU" theory; if right, 2 blocks/CU = 16 waves.
//  2. Weight/bias MFMA fragments hoisted out of the staging i-loop (i-invariant).
//  3. Softmax: 4-row transpose-reduce + butterfly + bpermute broadcast
//     (22 shfl/h01 instead of 48, same depth).
#define S_DIM 512
#define L_DIM 2048
#define NW 63
#define E_DIM 64
#define NH 8
#define HD 8

typedef __bf16 bf16_t;
typedef __bf16 bf16x8 __attribute__((ext_vector_type(8)));
typedef float f32x4 __attribute__((ext_vector_type(4)));

// 8 consecutive f32 -> bf16x8 MFMA fragment (RNE converts)
__device__ inline bf16x8 cvt8(const float* __restrict__ p) {
    float4 a = *(const float4*)p;
    float4 b = *(const float4*)(p + 4);
    bf16x8 r;
    r[0] = (bf16_t)a.x; r[1] = (bf16_t)a.y; r[2] = (bf16_t)a.z; r[3] = (bf16_t)a.w;
    r[4] = (bf16_t)b.x; r[5] = (bf16_t)b.y; r[6] = (bf16_t)b.z; r[7] = (bf16_t)b.w;
    return r;
}

// Register transpose-reduce (sum) over 32 items spread across 64 lanes.
#define RSTEP(B, CNT)                                              \
    {                                                              \
        bool up = (lane & B) != 0;                                 \
        _Pragma("unroll") for (int i = 0; i < CNT; ++i)            \
        {                                                          \
            float keep = up ? p[2 * i + 1] : p[2 * i];             \
            float send = up ? p[2 * i] : p[2 * i + 1];             \
            p[i] = keep + __shfl_xor(send, B, 64);                 \
        }                                                          \
    }

__global__ __launch_bounds__(512, 2) void swa_fused(
    const float* __restrict__ q, const float* __restrict__ k,
    const float* __restrict__ v, const float* __restrict__ w,
    const float* __restrict__ bias, const float* __restrict__ wout,
    const float* __restrict__ bout, float* __restrict__ out)
{
    // kp_s/vp_s: per-head [2][512][8] bf16, 16B rows. ds_read_b128 at
    // t = lane + 64j: each aligned 8-lane group hits 8 distinct bank-quads
    // (quad = t&7) -> conflict-free, no padding needed.
    __shared__ __align__(16) bf16_t kp_s[2][S_DIM][8];
    __shared__ __align__(16) bf16_t vp_s[2][S_DIM][8];
    __shared__ float  qp_s[32][64];      // this tile's scaled qp, fp32
    __shared__ float  ctx_s[32][68];
    __shared__ bf16_t wo_t[64][66];      // wo transposed: [f][e]
    __shared__ float  bo_s[64];

    int tid  = threadIdx.x;
    int lane = tid & 63, wave = tid >> 6;   // 8 waves
    int bid  = blockIdx.x;
    int n    = bid >> 4;             // 63 windows x 16 row-tiles
    int tile = bid & 15;
    int srow0 = tile * 32;

    float* out_x  = out;
    float* out_aw = out + (size_t)S_DIM * NW * E_DIM;

    // ---- stage out-proj (transposed) + bias; first hp barrier orders these ----
#pragma unroll
    for (int i = 0; i < 8; ++i) {
        int idx = tid + i * 512;                    // idx = e*64 + f
        wo_t[idx & 63][idx >> 6] = (bf16_t)wout[idx];
    }
    if (tid < 64) bo_s[tid] = bout[tid];

    int ml = lane & 15, quad = lane >> 4;

    // ---- qp for this block's 32 rows via MFMA (waves 0,1), scale*log2e folded ----
    if (wave < 2) {
        int s0 = srow0 + wave * 16;
        f32x4 acc[4];
#pragma unroll
        for (int et = 0; et < 4; ++et) {
            float bv = bias[et * 16 + ml];
            acc[et] = (f32x4){bv, bv, bv, bv};
        }
        int arow = (s0 + ml) * L_DIM + 32 * n + quad * 8;
#pragma unroll
        for (int k0 = 0; k0 < 64; k0 += 32) {
            bf16x8 afrag = cvt8(q + arow + k0);
#pragma unroll
            for (int et = 0; et < 4; ++et) {
                bf16x8 bfrag = cvt8(w + (et * 16 + ml) * 64 + k0 + quad * 8);
                acc[et] = __builtin_amdgcn_mfma_f32_16x16x32_bf16(afrag, bfrag, acc[et], 0, 0, 0);
            }
        }
        const float cs = 0.35355339059327373f * 1.4426950408889634f;
#pragma unroll
        for (int et = 0; et < 4; ++et)
#pragma unroll
            for (int rr = 0; rr < 4; ++rr)
                qp_s[16 * wave + quad * 4 + rr][et * 16 + ml] = acc[et][rr] * cs;
    }

    float accw[32];   // attn-weight mean accumulator [r][j], r<4
#pragma unroll
    for (int i = 0; i < 32; ++i) accw[i] = 0.f;

    for (int hp = 0; hp < 4; ++hp) {
        __syncthreads();   // prev readers done (also orders qp/wo/bo stores at hp=0)

        // ---- stage kp/vp[2][512][8] for heads {2hp, 2hp+1} via MFMA ----
        {
            float bk0 = bias[64 + hp * 16 + ml];
            float bv0 = bias[128 + hp * 16 + ml];
            // weight fragments are i-invariant: hoist out of the row loop
            bf16x8 bkf0 = cvt8(w + (64 + hp * 16 + ml) * 64 + quad * 8);
            bf16x8 bkf1 = cvt8(w + (64 + hp * 16 + ml) * 64 + 32 + quad * 8);
            bf16x8 bvf0 = cvt8(w + (128 + hp * 16 + ml) * 64 + quad * 8);
            bf16x8 bvf1 = cvt8(w + (128 + hp * 16 + ml) * 64 + 32 + quad * 8);
            int hsel = ml >> 3, dsel = ml & 7;
#pragma unroll
            for (int i = 0; i < 4; ++i) {
                int s0 = wave * 64 + 16 * i;
                int arow = (s0 + ml) * L_DIM + 32 * n + quad * 8;
                f32x4 kacc = (f32x4){bk0, bk0, bk0, bk0};
                f32x4 vacc = (f32x4){bv0, bv0, bv0, bv0};
                kacc = __builtin_amdgcn_mfma_f32_16x16x32_bf16(cvt8(k + arow), bkf0, kacc, 0, 0, 0);
                kacc = __builtin_amdgcn_mfma_f32_16x16x32_bf16(cvt8(k + arow + 32), bkf1, kacc, 0, 0, 0);
                vacc = __builtin_amdgcn_mfma_f32_16x16x32_bf16(cvt8(v + arow), bvf0, vacc, 0, 0, 0);
                vacc = __builtin_amdgcn_mfma_f32_16x16x32_bf16(cvt8(v + arow + 32), bvf1, vacc, 0, 0, 0);
#pragma unroll
                for (int rr = 0; rr < 4; ++rr) {
                    kp_s[hsel][s0 + quad * 4 + rr][dsel] = (bf16_t)kacc[rr];
                    vp_s[hsel][s0 + quad * 4 + rr][dsel] = (bf16_t)vacc[rr];
                }
            }
        }
        __syncthreads();

#pragma unroll
        for (int h01 = 0; h01 < 2; ++h01) {
            int h = hp * 2 + h01;

            // scores (log2 domain; scale*log2e folded into qp).
            // K streamed in two 32-reg halves to keep live set small.
            float sc[32];
#pragma unroll
            for (int half = 0; half < 2; ++half) {
                float kreg[32];
#pragma unroll
                for (int j = 0; j < 4; ++j) {
                    int t = lane + 64 * (half * 4 + j);
                    bf16x8 kb = *(const bf16x8*)(&kp_s[h01][t][0]);
#pragma unroll
                    for (int d = 0; d < 8; ++d) kreg[j * 8 + d] = (float)kb[d];
                }
#pragma unroll
                for (int r = 0; r < 4; ++r) {
                    float qreg[8];
#pragma unroll
                    for (int d = 0; d < 8; ++d) qreg[d] = qp_s[wave * 4 + r][h * 8 + d];
#pragma unroll
                    for (int j = 0; j < 4; ++j) {
                        float s = 0.f;
#pragma unroll
                        for (int d = 0; d < 8; ++d) s = fmaf(qreg[d], kreg[j * 8 + d], s);
                        sc[r * 8 + half * 4 + j] = s;
                    }
                }
            }

            // ---- softmax over 512 keys per row; 4 rows share one wave ----
            // in-lane partial max per row
            float pm[4];
#pragma unroll
            for (int r = 0; r < 4; ++r) {
                float m0 = fmaxf(fmaxf(sc[r * 8 + 0], sc[r * 8 + 1]),
                                 fmaxf(sc[r * 8 + 2], sc[r * 8 + 3]));
                float m1 = fmaxf(fmaxf(sc[r * 8 + 4], sc[r * 8 + 5]),
                                 fmaxf(sc[r * 8 + 6], sc[r * 8 + 7]));
                pm[r] = fmaxf(m0, m1);
            }
            {   // 4-item transpose-reduce (max): 3 shfl + 4-step butterfly
                bool up1 = (lane & 1) != 0;
#pragma unroll
                for (int i = 0; i < 2; ++i) {
                    float keep = up1 ? pm[2 * i + 1] : pm[2 * i];
                    float send = up1 ? pm[2 * i] : pm[2 * i + 1];
                    pm[i] = fmaxf(keep, __shfl_xor(send, 1, 64));
                }
                bool up2 = (lane & 2) != 0;
                float keep = up2 ? pm[1] : pm[0];
                float send = up2 ? pm[0] : pm[1];
                pm[0] = fmaxf(keep, __shfl_xor(send, 2, 64));
#pragma unroll
                for (int b = 4; b < 64; b <<= 1)
                    pm[0] = fmaxf(pm[0], __shfl_xor(pm[0], b, 64));
            }
            float mx[4];
#pragma unroll
            for (int r = 0; r < 4; ++r) mx[r] = __shfl(pm[0], (lane & ~3) | r, 64);

            // exponentials + in-lane sums
            float ps[4];
#pragma unroll
            for (int r = 0; r < 4; ++r) {
                float l = 0.f;
#pragma unroll
                for (int j = 0; j < 8; ++j) {
                    float e = exp2f(sc[r * 8 + j] - mx[r]);
                    sc[r * 8 + j] = e;
                    l += e;
                }
                ps[r] = l;
            }
            {   // 4-item transpose-reduce (sum)
                bool up1 = (lane & 1) != 0;
#pragma unroll
                for (int i = 0; i < 2; ++i) {
                    float keep = up1 ? ps[2 * i + 1] : ps[2 * i];
                    float send = up1 ? ps[2 * i] : ps[2 * i + 1];
                    ps[i] = keep + __shfl_xor(send, 1, 64);
                }
                bool up2 = (lane & 2) != 0;
                float keep = up2 ? ps[1] : ps[0];
                float send = up2 ? ps[0] : ps[1];
                ps[0] = keep + __shfl_xor(send, 2, 64);
#pragma unroll
                for (int b = 4; b < 64; b <<= 1) ps[0] += __shfl_xor(ps[0], b, 64);
            }
#pragma unroll
            for (int r = 0; r < 4; ++r) {
                float inv = 1.0f / __shfl(ps[0], (lane & ~3) | r, 64);
#pragma unroll
                for (int j = 0; j < 8; ++j) {
                    float a = sc[r * 8 + j] * inv;
                    sc[r * 8 + j] = a;
                    accw[r * 8 + j] = fmaf(a, 0.125f, accw[r * 8 + j]);
                }
            }

            // ctx partials from LDS V, then register transpose-reduce (32 items)
            float p[32];
#pragma unroll
            for (int i = 0; i < 32; ++i) p[i] = 0.f;
#pragma unroll
            for (int j = 0; j < 8; ++j) {
                int t = lane + 64 * j;
                bf16x8 vb = *(const bf16x8*)(&vp_s[h01][t][0]);
                float vr[8];
#pragma unroll
                for (int d = 0; d < 8; ++d) vr[d] = (float)vb[d];
#pragma unroll
                for (int r = 0; r < 4; ++r) {
                    float a = sc[r * 8 + j];
#pragma unroll
                    for (int d = 0; d < 8; ++d)
                        p[r * 8 + d] = fmaf(a, vr[d], p[r * 8 + d]);
                }
            }
            RSTEP(1, 16) RSTEP(2, 8) RSTEP(4, 4) RSTEP(8, 2) RSTEP(16, 1)
            p[0] += __shfl_xor(p[0], 32, 64);
            // lane&31 holds ctx for (r = (lane&31)>>3, d = lane&7); halves identical
            if (lane < 32)
                ctx_s[wave * 4 + (lane >> 3)][h * 8 + (lane & 7)] = p[0];
        }
    }
    __syncthreads();

    // ---- attn_weights [NW][S][S] f32: lanes contiguous in t -> coalesced ----
#pragma unroll
    for (int r = 0; r < 4; ++r) {
        int s = srow0 + wave * 4 + r;
        float* dst = out_aw + ((size_t)(n * S_DIM + s)) * S_DIM + lane;
#pragma unroll
        for (int j = 0; j < 8; ++j) dst[64 * j] = accw[r * 8 + j];
    }

    // ---- out projection: x[s][e] = sum_f ctx[s][f] * Wout[e][f] + bout[e] ----
    int so = tid >> 4;   // 0..31
    int eb = tid & 15;
    float xacc[4];
#pragma unroll
    for (int kk = 0; kk < 4; ++kk) xacc[kk] = bo_s[eb + 16 * kk];
#pragma unroll
    for (int f = 0; f < 64; ++f) {
        float c = ctx_s[so][f];
#pragma unroll
        for (int kk = 0; kk < 4; ++kk)
            xacc[kk] = fmaf(c, (float)wo_t[f][eb + 16 * kk], xacc[kk]);
    }
    int sg = srow0 + so;
#pragma unroll
    for (int kk = 0; kk < 4; ++kk)
        out_x[((size_t)sg * NW + n) * E_DIM + eb + 16 * kk] = xacc[kk];
}

extern "C" void kernel_launch(void* const* d_in, const int* in_sizes, int n_in,
                              void* d_out, int out_size, void* d_ws, size_t ws_size,
                              hipStream_t stream) {
    const float* q  = (const float*)d_in[0];
    const float* k  = (const float*)d_in[1];
    const float* v  = (const float*)d_in[2];
    const float* w  = (const float*)d_in[3];
    const float* b  = (const float*)d_in[4];
    const float* wo = (const float*)d_in[5];
    const float* bo = (const float*)d_in[6];
    float* out = (float*)d_out;

    // 63 windows * 16 row-tiles = 1008 blocks of 512 threads.
    hipLaunchKernelGGL(swa_fused, dim3(NW * 16), dim3(512), 0, stream,
                       q, k, v, w, b, wo, bo, out);
}